// Round 22
// baseline (421.889 us; speedup 1.0000x reference)
//
#include <hip/hip_runtime.h>

#define B_ 16
#define C_ 64
#define H_ 128
#define W_ 256
#define K_ 9
#define KDIM_ (K_*C_)            // 576

typedef __attribute__((ext_vector_type(8))) short short8_t;
typedef __attribute__((ext_vector_type(4))) float f32x4;

static __device__ __forceinline__ float bf2f(unsigned short u) {
  union { unsigned int i; float f; } v; v.i = ((unsigned int)u) << 16; return v.f;
}
static __device__ __forceinline__ unsigned short f2bf(float f) {
  union { float f; unsigned int i; } v; v.f = f;
  unsigned int r = v.i + 0x7FFF + ((v.i >> 16) & 1);   // RNE
  return (unsigned short)(r >> 16);
}

// async global->LDS, 16B per lane; lds base wave-uniform, lanes fill +lane*16
static __device__ __forceinline__ void gload_lds16(const void* g, void* l) {
  __builtin_amdgcn_global_load_lds(
      (const __attribute__((address_space(1))) unsigned int*)g,
      (__attribute__((address_space(3))) unsigned int*)l, 16, 0, 0);
}

// All 4 weight tensors [co][ci][kk] fp32 -> A2 chunk layout (16B chunk = 8
// consecutive k for one co): A2[((k>>3)*64+co)*8 + (k&7)], k = kk*64+ci.
// Also zeroes the 1KB zeropage.
__global__ __launch_bounds__(256) void prep_w_all(const float* __restrict__ w0,
                                                  const float* __restrict__ w1,
                                                  const float* __restrict__ w2,
                                                  const float* __restrict__ w3,
                                                  unsigned short* __restrict__ A2,
                                                  float* __restrict__ ZPf) {
  if (blockIdx.y == 0 && blockIdx.x == 0) ZPf[threadIdx.x] = 0.f;  // 1KB zeropage
  int idx = blockIdx.x * 256 + threadIdx.x;
  if (idx >= C_ * KDIM_) return;
  int which = blockIdx.y;
  const float* w = (which == 0) ? w0 : (which == 1) ? w1 : (which == 2) ? w2 : w3;
  unsigned short* out = A2 + (size_t)which * (C_ * KDIM_);
  int co = idx / KDIM_, k = idx % KDIM_;
  int ci = k & 63, kk = k >> 6;
  out[((size_t)(k >> 3) * 64 + co) * 8 + (k & 7)] =
      f2bf(w[((size_t)co * C_ + ci) * K_ + kk]);
}

// fp32 NCHW -> bf16 ci-minor [b][h][w][ci]
__global__ __launch_bounds__(256) void transpose_in(const float* __restrict__ x,
                                                    unsigned short* __restrict__ Xt) {
  __shared__ float tile[64][65];
  const int w0 = blockIdx.x * 64, h = blockIdx.y, b = blockIdx.z;
  const int t = threadIdx.x;
#pragma unroll
  for (int rep = 0; rep < 16; ++rep) {
    int idx = rep * 256 + t;
    int ci = idx >> 6, wl = idx & 63;
    tile[ci][wl] = x[((size_t)(b * C_ + ci) * H_ + h) * W_ + w0 + wl];
  }
  __syncthreads();
#pragma unroll
  for (int rep = 0; rep < 8; ++rep) {
    int idx = rep * 256 + t;
    int wl = idx >> 5, cp = idx & 31;
    unsigned v = (unsigned)f2bf(tile[cp*2][wl]) | ((unsigned)f2bf(tile[cp*2+1][wl]) << 16);
    *(unsigned*)(Xt + ((size_t)(b * H_ + h) * W_ + w0 + wl) * C_ + cp * 2) = v;
  }
}

// ===== conv9: conv8 + A-fragments for steps 0..8 held in registers =====
// 512 thr / 8 waves (2/SIMD), grid 256, LDS 143KB. Wave owns 32 pos x 64 co.
// areg[9][4] (144 VGPR) loaded once from LDS after the first barrier; steps
// 9..17 read A from LDS. LDS reads/supertile/CU: 864 -> 576 (below the MFMA
// pipe's 5587 cyc) — conv back to MFMA-bound WITH 2-wave/SIMD hiding.
// Counted barrier: per-wave epilogue = 8 stores -> vmcnt(8) (T4).
template<int QLEN>
__global__ __launch_bounds__(512, 1) void conv9(const unsigned short* __restrict__ X,
                                                unsigned short* __restrict__ Y,
                                                const unsigned short* __restrict__ A2,
                                                const float* __restrict__ bias,
                                                const unsigned short* __restrict__ ZP) {
  constexpr int SEGROWS = 256 / QLEN;              // 1 or 2 strips
  constexpr int NG      = (256 + 8 * SEGROWS) / 8; // 33 or 34 groups of 1KB
  __shared__ __align__(16) char lds[73728 + 2 * 34816];
  char* Alds  = lds;
  char* xbuf0 = lds + 73728;
  char* xbuf1 = lds + 73728 + 34816;

  const int t = threadIdx.x;
  const int lane = t & 63, wv = t >> 6;            // wv 0..7
  const int llo = lane & 15, lhi = lane >> 4;

  // ---- A -> LDS: 72 x 1KB groups, 9 per wave ----
#pragma unroll
  for (int i = 0; i < 9; ++i) {
    int m = wv + i * 8;
    gload_lds16(A2 + (size_t)m * 512 + lane * 8, Alds + m * 1024);
  }

  // stage super-tile u into dst (groups split across 8 waves)
  auto stageX = [&](char* dst, int u) {
#pragma unroll
    for (int i = 0; i < 5; ++i) {
      int gl = wv + i * 8;
      if (gl < NG) {
        int strip = (SEGROWS == 2 && gl >= 17) ? 1 : 0;
        int gg = gl - strip * 17;
        int r = gg * 8 + (lane >> 3);            // row within strip
        int slot = lane & 7;
        int chunk = slot ^ (r & 7);
        int q = r - 4;
        int rowId = (SEGROWS == 1) ? u : u * 2 + strip;
        const void* src = ((unsigned)q < (unsigned)QLEN)
            ? (const void*)(X + (size_t)rowId * (QLEN * 64) + (size_t)q * 64 + chunk * 8)
            : (const void*)(ZP + slot * 8);
        gload_lds16(src, dst + strip * 17408 + gg * 1024);
      }
    }
  };

  float4 bv[4];
#pragma unroll
  for (int j = 0; j < 4; ++j) bv[j] = *(const float4*)(bias + j * 16 + lhi * 4);

  const int stripoff = (SEGROWS == 1) ? 0 : (wv >> 2) * 17408;
  const int posbase  = (SEGROWS == 1) ? wv * 32 : (wv & 3) * 32;

  const int u0 = blockIdx.x * 8;
  stageX(xbuf0, u0);
  __syncthreads();   // full drain once: A + stage(0)

  // ---- A fragments for steps 0..8 -> registers (from LDS, once) ----
  short8_t areg[9][4];
#pragma unroll
  for (int st = 0; st < 9; ++st)
#pragma unroll
    for (int j = 0; j < 4; ++j)
      areg[st][j] = *(const short8_t*)(Alds + st * 4096 + lhi * 1024 + j * 256 + llo * 16);

  for (int tt = 0; tt < 8; ++tt) {
    const int u = u0 + tt;
    char* cur = (tt & 1) ? xbuf1 : xbuf0;
    char* nxt = (tt & 1) ? xbuf0 : xbuf1;
    if (tt < 7) stageX(nxt, u + 1);              // issue BEFORE compute

    const char* xb = cur + stripoff;
    f32x4 acc[2][4];
#pragma unroll
    for (int i = 0; i < 2; ++i)
#pragma unroll
      for (int j = 0; j < 4; ++j) { f32x4 z = {0.f,0.f,0.f,0.f}; acc[i][j] = z; }

#pragma unroll
    for (int step = 0; step < 18; ++step) {
      const int kk = step >> 1;
      const int cg = (step & 1) * 4 + lhi;
      short8_t a[4], f[2];
      if (step < 9) {
#pragma unroll
        for (int j = 0; j < 4; ++j) a[j] = areg[step][j];
      } else {
#pragma unroll
        for (int j = 0; j < 4; ++j)
          a[j] = *(const short8_t*)(Alds + step * 4096 + lhi * 1024 + j * 256 + llo * 16);
      }
#pragma unroll
      for (int i = 0; i < 2; ++i) {
        int r = posbase + i * 16 + llo + kk;
        f[i] = *(const short8_t*)(xb + r * 128 + ((cg ^ (r & 7)) << 4));
      }
#pragma unroll
      for (int i = 0; i < 2; ++i)
#pragma unroll
        for (int j = 0; j < 4; ++j)
          acc[i][j] = __builtin_amdgcn_mfma_f32_16x16x32_bf16(a[j], f[i], acc[i][j], 0, 0, 0);
    }

    // epilogue: +bias, pack 4 consecutive co, 8B stores (8 per wave)
    const int outRow = (SEGROWS == 1) ? u : u * 2 + (wv >> 2);
    const size_t rowbase = (size_t)outRow * (QLEN * 64);
#pragma unroll
    for (int j = 0; j < 4; ++j) {
#pragma unroll
      for (int i = 0; i < 2; ++i) {
        const int q = posbase + i * 16 + llo;
        float v0 = acc[i][j][0] + bv[j].x;
        float v1 = acc[i][j][1] + bv[j].y;
        float v2 = acc[i][j][2] + bv[j].z;
        float v3 = acc[i][j][3] + bv[j].w;
        unsigned lo, hi;
        asm("v_cvt_pk_bf16_f32 %0, %1, %2" : "=v"(lo) : "v"(v0), "v"(v1));
        asm("v_cvt_pk_bf16_f32 %0, %1, %2" : "=v"(hi) : "v"(v2), "v"(v3));
        uint2 ov; ov.x = lo; ov.y = hi;
        *(uint2*)(Y + rowbase + (size_t)q * 64 + j * 16 + lhi * 4) = ov;
      }
    }
    if (tt < 7) {
      // counted barrier: the 8 newest VMEM ops are this wave's stores;
      // waiting to <=8 retires all its stage(t+1) loads (in-order retire).
      asm volatile("s_waitcnt vmcnt(8)\n\ts_barrier" ::: "memory");
    }
  }
}

// ===== scan along OUTER dim P of [b][P][Q][ci], 4 ci/thread, depth-16 =====
// TRANS=1: write result transposed to [b][Q][P][ci] (outT) instead of in-place.
template<int PLEN, int QLEN, int REV, int TRANS>
__global__ __launch_bounds__(128) void scan_o4(unsigned short* __restrict__ conv,
                                               const unsigned short* __restrict__ prev,
                                               unsigned short* __restrict__ outT) {
  int idx = blockIdx.x * 128 + threadIdx.x;     // B * QLEN * 16
  int cq = idx & 15;
  int q  = (idx >> 4) % QLEN;
  int b  = idx / (16 * QLEN);
  const ptrdiff_t dp = (REV ? -1 : 1) * (ptrdiff_t)(QLEN * 64);
  const int p0 = REV ? PLEN - 1 : 0;
  size_t off = ((size_t)(b * PLEN + p0) * QLEN + q) * 64 + cq * 4;
  size_t offT = 0; ptrdiff_t dpT = 0;
  if (TRANS) {
    offT = ((size_t)(b * QLEN + q) * PLEN + p0) * 64 + cq * 4;
    dpT = (REV ? -1 : 1) * (ptrdiff_t)64;
  }
  uint2 pv = *(const uint2*)(prev + off);
  if (TRANS) *(uint2*)(outT + offT) = pv; else *(uint2*)(conv + off) = pv;
  float y0 = bf2f((unsigned short)pv.x), y1 = bf2f((unsigned short)(pv.x >> 16));
  float y2 = bf2f((unsigned short)pv.y), y3 = bf2f((unsigned short)(pv.y >> 16));
  uint2 c[16];
#pragma unroll
  for (int j = 0; j < 16; ++j) c[j] = *(const uint2*)(conv + off + (ptrdiff_t)(j + 1) * dp);
  for (int base = 1; base < PLEN; base += 16) {
#pragma unroll
    for (int j = 0; j < 16; ++j) {
      int s = base + j;
      if (s < PLEN) {
        off += dp;
        if (TRANS) offT += dpT;
        y0 = fmaxf(bf2f((unsigned short)c[j].x) + y0, 0.f);
        y1 = fmaxf(bf2f((unsigned short)(c[j].x >> 16)) + y1, 0.f);
        y2 = fmaxf(bf2f((unsigned short)c[j].y) + y2, 0.f);
        y3 = fmaxf(bf2f((unsigned short)(c[j].y >> 16)) + y3, 0.f);
        uint2 ov;
        ov.x = (unsigned)f2bf(y0) | ((unsigned)f2bf(y1) << 16);
        ov.y = (unsigned)f2bf(y2) | ((unsigned)f2bf(y3) << 16);
        if (TRANS) *(uint2*)(outT + offT) = ov; else *(uint2*)(conv + off) = ov;
        if (s + 16 < PLEN) c[j] = *(const uint2*)(conv + off + 16 * dp);
      }
    }
  }
}

// ===== scan_o2: in-place scan, 2 ci/thread (sweep 3) =====
template<int PLEN, int QLEN, int REV>
__global__ __launch_bounds__(128) void scan_o2(unsigned short* __restrict__ conv,
                                               const unsigned short* __restrict__ prev) {
  int idx = blockIdx.x * 128 + threadIdx.x;     // B * QLEN * 32
  int cp = idx & 31;
  int q  = (idx >> 5) % QLEN;
  int b  = idx / (32 * QLEN);
  const ptrdiff_t dp = (REV ? -1 : 1) * (ptrdiff_t)(QLEN * 64);
  const int p0 = REV ? PLEN - 1 : 0;
  size_t off = ((size_t)(b * PLEN + p0) * QLEN + q) * 64 + cp * 2;
  unsigned pv = *(const unsigned*)(prev + off);
  *(unsigned*)(conv + off) = pv;
  float y0 = bf2f((unsigned short)pv), y1 = bf2f((unsigned short)(pv >> 16));
  unsigned c[16];
#pragma unroll
  for (int j = 0; j < 16; ++j) c[j] = *(const unsigned*)(conv + off + (ptrdiff_t)(j + 1) * dp);
  for (int base = 1; base < PLEN; base += 16) {
#pragma unroll
    for (int j = 0; j < 16; ++j) {
      int s = base + j;
      if (s < PLEN) {
        off += dp;
        y0 = fmaxf(bf2f((unsigned short)c[j]) + y0, 0.f);
        y1 = fmaxf(bf2f((unsigned short)(c[j] >> 16)) + y1, 0.f);
        *(unsigned*)(conv + off) = (unsigned)f2bf(y0) | ((unsigned)f2bf(y1) << 16);
        if (s + 16 < PLEN) c[j] = *(const unsigned*)(conv + off + 16 * dp);
      }
    }
  }
}

// ===== scan4t: fused sweep-4 scan (rev along w on [b][w][h][ci]) + fp32 NCHW
// output via 32KB LDS tile; flush = full 256B-contiguous NCHW rows.
__global__ __launch_bounds__(128) void scan4t(const unsigned short* __restrict__ conv,
                                              const unsigned short* __restrict__ prev,
                                              float* __restrict__ out) {
  __shared__ unsigned tile[64 * 128];   // slot = wl*128 + hh*32 + (cp^(wl&31))
  const int t = threadIdx.x;
  const int cp = t & 31, hh = t >> 5;
  const int hg = blockIdx.x, b = blockIdx.y;
  const int h = hg * 4 + hh;
  const int wvid = t >> 6, wl = t & 63;

  const ptrdiff_t dp = -(ptrdiff_t)(H_ * 64);
  size_t off = ((size_t)(b * W_ + (W_ - 1)) * H_ + h) * 64 + cp * 2;

  auto flushChunk = [&](int w0) {
    __syncthreads();
    for (int p = 0; p < 64; ++p) {
      int combo = p * 2 + wvid;
      int fh = combo >> 5, fcp = combo & 31;
      unsigned v = tile[wl * 128 + fh * 32 + (fcp ^ (wl & 31))];
      size_t ob = ((size_t)(b * C_ + fcp * 2) * H_ + hg * 4 + fh) * W_ + w0 + wl;
      out[ob] = bf2f((unsigned short)v);
      out[ob + (size_t)H_ * W_] = bf2f((unsigned short)(v >> 16));
    }
    __syncthreads();
  };

  // s = 0 (w = 255): passthrough from prev, bit-exact
  unsigned pv = *(const unsigned*)(prev + off);
  float y0 = bf2f((unsigned short)pv), y1 = bf2f((unsigned short)(pv >> 16));
  tile[63 * 128 + hh * 32 + (cp ^ 31)] = pv;

  unsigned c[16];
#pragma unroll
  for (int j = 0; j < 16; ++j)
    c[j] = *(const unsigned*)(conv + off + (ptrdiff_t)(j + 1) * dp);

  for (int base = 1; base < W_; base += 16) {
#pragma unroll
    for (int j = 0; j < 16; ++j) {
      int s = base + j;
      off += dp;
      unsigned cv = c[j];
      y0 = fmaxf(bf2f((unsigned short)cv) + y0, 0.f);
      y1 = fmaxf(bf2f((unsigned short)(cv >> 16)) + y1, 0.f);
      int w = W_ - 1 - s;
      tile[(w & 63) * 128 + hh * 32 + (cp ^ (w & 31))] =
          (unsigned)f2bf(y0) | ((unsigned)f2bf(y1) << 16);
      if (s + 16 < W_) c[j] = *(const unsigned*)(conv + off + 16 * dp);
      if ((s & 63) == 63) flushChunk(w);   // w = 192,128,64,0
    }
  }
}

extern "C" void kernel_launch(void* const* d_in, const int* in_sizes, int n_in,
                              void* d_out, int out_size, void* d_ws, size_t ws_size,
                              hipStream_t stream) {
  const float* x    = (const float*)d_in[0];
  const float* w_ud = (const float*)d_in[1];
  const float* b_ud = (const float*)d_in[2];
  const float* w_du = (const float*)d_in[3];
  const float* b_du = (const float*)d_in[4];
  const float* w_lr = (const float*)d_in[5];
  const float* b_lr = (const float*)d_in[6];
  const float* w_rl = (const float*)d_in[7];
  const float* b_rl = (const float*)d_in[8];

  // ws: A[0,64M) Bb[64M,128M) Cc[128M,192M) A2 @192M, zeropage @192M+1M
  unsigned short* A  = (unsigned short*)d_ws;
  unsigned short* Bb = (unsigned short*)((char*)d_ws + 67108864);
  unsigned short* Cc = (unsigned short*)((char*)d_ws + 134217728);
  unsigned short* A2 = (unsigned short*)((char*)d_ws + 201326592);
  unsigned short* ZP = (unsigned short*)((char*)d_ws + 202375168);
  unsigned short* A2_ud = A2 + 0 * (C_ * KDIM_);
  unsigned short* A2_du = A2 + 1 * (C_ * KDIM_);
  unsigned short* A2_lr = A2 + 2 * (C_ * KDIM_);
  unsigned short* A2_rl = A2 + 3 * (C_ * KDIM_);

  dim3 pg((C_ * KDIM_ + 255) / 256, 4);
  prep_w_all<<<pg, 256, 0, stream>>>(w_ud, w_du, w_lr, w_rl, A2, (float*)ZP);

  transpose_in<<<dim3(4, H_, B_), 256, 0, stream>>>(x, A);

  // sweep 1 (ud): conv along W on [b][h][w][ci]; scan fwd along h
  conv9<W_><<<256, 512, 0, stream>>>(A, Bb, A2_ud, b_ud, ZP);
  scan_o4<H_, W_, 0, 0><<<512, 128, 0, stream>>>(Bb, A, nullptr);

  // sweep 2 (du): conv along W; scan rev along h, WRITE TRANSPOSED -> [b][w][h][ci]
  conv9<W_><<<256, 512, 0, stream>>>(Bb, Cc, A2_du, b_du, ZP);
  scan_o4<H_, W_, 1, 1><<<512, 128, 0, stream>>>(Cc, Bb, A);

  // sweep 3 (lr): conv along H (inner dim of flipped layout); scan fwd along w
  conv9<H_><<<256, 512, 0, stream>>>(A, Bb, A2_lr, b_lr, ZP);
  scan_o2<W_, H_, 0><<<512, 128, 0, stream>>>(Bb, A);

  // sweep 4 (rl): conv along H; scan rev along w, fused with NCHW fp32 output
  conv9<H_><<<256, 512, 0, stream>>>(Bb, Cc, A2_rl, b_rl, ZP);
  scan4t<<<dim3(32, B_), 128, 0, stream>>>(Cc, Bb, (float*)d_out);
}

// Round 23
// 329.952 us; speedup vs baseline: 1.2786x; 1.2786x over previous
//
#include <hip/hip_runtime.h>

#define B_ 16
#define C_ 64
#define H_ 128
#define W_ 256
#define K_ 9
#define KDIM_ (K_*C_)            // 576

typedef __attribute__((ext_vector_type(8))) short short8_t;
typedef __attribute__((ext_vector_type(4))) float f32x4;

static __device__ __forceinline__ float bf2f(unsigned short u) {
  union { unsigned int i; float f; } v; v.i = ((unsigned int)u) << 16; return v.f;
}
static __device__ __forceinline__ unsigned short f2bf(float f) {
  union { float f; unsigned int i; } v; v.f = f;
  unsigned int r = v.i + 0x7FFF + ((v.i >> 16) & 1);   // RNE
  return (unsigned short)(r >> 16);
}

// async global->LDS, 16B per lane; lds base wave-uniform, lanes fill +lane*16
static __device__ __forceinline__ void gload_lds16(const void* g, void* l) {
  __builtin_amdgcn_global_load_lds(
      (const __attribute__((address_space(1))) unsigned int*)g,
      (__attribute__((address_space(3))) unsigned int*)l, 16, 0, 0);
}

// All 4 weight tensors [co][ci][kk] fp32 -> A2 chunk layout (16B chunk = 8
// consecutive k for one co): A2[((k>>3)*64+co)*8 + (k&7)], k = kk*64+ci.
// Also zeroes the 1KB zeropage.
__global__ __launch_bounds__(256) void prep_w_all(const float* __restrict__ w0,
                                                  const float* __restrict__ w1,
                                                  const float* __restrict__ w2,
                                                  const float* __restrict__ w3,
                                                  unsigned short* __restrict__ A2,
                                                  float* __restrict__ ZPf) {
  if (blockIdx.y == 0 && blockIdx.x == 0) ZPf[threadIdx.x] = 0.f;  // 1KB zeropage
  int idx = blockIdx.x * 256 + threadIdx.x;
  if (idx >= C_ * KDIM_) return;
  int which = blockIdx.y;
  const float* w = (which == 0) ? w0 : (which == 1) ? w1 : (which == 2) ? w2 : w3;
  unsigned short* out = A2 + (size_t)which * (C_ * KDIM_);
  int co = idx / KDIM_, k = idx % KDIM_;
  int ci = k & 63, kk = k >> 6;
  out[((size_t)(k >> 3) * 64 + co) * 8 + (k & 7)] =
      f2bf(w[((size_t)co * C_ + ci) * K_ + kk]);
}

// fp32 NCHW -> bf16 ci-minor [b][h][w][ci]
__global__ __launch_bounds__(256) void transpose_in(const float* __restrict__ x,
                                                    unsigned short* __restrict__ Xt) {
  __shared__ float tile[64][65];
  const int w0 = blockIdx.x * 64, h = blockIdx.y, b = blockIdx.z;
  const int t = threadIdx.x;
#pragma unroll
  for (int rep = 0; rep < 16; ++rep) {
    int idx = rep * 256 + t;
    int ci = idx >> 6, wl = idx & 63;
    tile[ci][wl] = x[((size_t)(b * C_ + ci) * H_ + h) * W_ + w0 + wl];
  }
  __syncthreads();
#pragma unroll
  for (int rep = 0; rep < 8; ++rep) {
    int idx = rep * 256 + t;
    int wl = idx >> 5, cp = idx & 31;
    unsigned v = (unsigned)f2bf(tile[cp*2][wl]) | ((unsigned)f2bf(tile[cp*2+1][wl]) << 16);
    *(unsigned*)(Xt + ((size_t)(b * H_ + h) * W_ + w0 + wl) * C_ + cp * 2) = v;
  }
}

// ===== conv8: square-tile MFMA conv, 512 thr / 8 waves (2 waves/SIMD) =====
// Grid 256 (1 block/CU), LDS 143KB. Wave owns 32 positions x 64 co (acc 2x4).
// 2 waves/SIMD hide ds_read latency and barrier-arrival gaps. Counted barrier:
// per-wave epilogue = 8 stores -> vmcnt(8) retires all of this wave's
// stage(t+1) loads while stores stay in flight (T4).
template<int QLEN>
__global__ __launch_bounds__(512, 1) void conv8(const unsigned short* __restrict__ X,
                                                unsigned short* __restrict__ Y,
                                                const unsigned short* __restrict__ A2,
                                                const float* __restrict__ bias,
                                                const unsigned short* __restrict__ ZP) {
  constexpr int SEGROWS = 256 / QLEN;              // 1 or 2 strips
  constexpr int NG      = (256 + 8 * SEGROWS) / 8; // 33 or 34 groups of 1KB
  __shared__ __align__(16) char lds[73728 + 2 * 34816];
  char* Alds  = lds;
  char* xbuf0 = lds + 73728;
  char* xbuf1 = lds + 73728 + 34816;

  const int t = threadIdx.x;
  const int lane = t & 63, wv = t >> 6;            // wv 0..7
  const int llo = lane & 15, lhi = lane >> 4;

  // ---- A -> LDS: 72 x 1KB groups, 9 per wave ----
#pragma unroll
  for (int i = 0; i < 9; ++i) {
    int m = wv + i * 8;
    gload_lds16(A2 + (size_t)m * 512 + lane * 8, Alds + m * 1024);
  }

  // stage super-tile u into dst (groups split across 8 waves)
  auto stageX = [&](char* dst, int u) {
#pragma unroll
    for (int i = 0; i < 5; ++i) {
      int gl = wv + i * 8;
      if (gl < NG) {
        int strip = (SEGROWS == 2 && gl >= 17) ? 1 : 0;
        int gg = gl - strip * 17;
        int r = gg * 8 + (lane >> 3);            // row within strip
        int slot = lane & 7;
        int chunk = slot ^ (r & 7);
        int q = r - 4;
        int rowId = (SEGROWS == 1) ? u : u * 2 + strip;
        const void* src = ((unsigned)q < (unsigned)QLEN)
            ? (const void*)(X + (size_t)rowId * (QLEN * 64) + (size_t)q * 64 + chunk * 8)
            : (const void*)(ZP + slot * 8);
        gload_lds16(src, dst + strip * 17408 + gg * 1024);
      }
    }
  };

  float4 bv[4];
#pragma unroll
  for (int j = 0; j < 4; ++j) bv[j] = *(const float4*)(bias + j * 16 + lhi * 4);

  const int stripoff = (SEGROWS == 1) ? 0 : (wv >> 2) * 17408;
  const int posbase  = (SEGROWS == 1) ? wv * 32 : (wv & 3) * 32;

  const int u0 = blockIdx.x * 8;
  stageX(xbuf0, u0);
  __syncthreads();   // full drain once: A + stage(0)

  for (int tt = 0; tt < 8; ++tt) {
    const int u = u0 + tt;
    char* cur = (tt & 1) ? xbuf1 : xbuf0;
    char* nxt = (tt & 1) ? xbuf0 : xbuf1;
    if (tt < 7) stageX(nxt, u + 1);              // issue BEFORE compute

    const char* xb = cur + stripoff;
    f32x4 acc[2][4];
#pragma unroll
    for (int i = 0; i < 2; ++i)
#pragma unroll
      for (int j = 0; j < 4; ++j) { f32x4 z = {0.f,0.f,0.f,0.f}; acc[i][j] = z; }

#pragma unroll
    for (int step = 0; step < 18; ++step) {
      const int kk = step >> 1;
      const int cg = (step & 1) * 4 + lhi;
      short8_t a[4], f[2];
#pragma unroll
      for (int j = 0; j < 4; ++j)
        a[j] = *(const short8_t*)(Alds + step * 4096 + lhi * 1024 + j * 256 + llo * 16);
#pragma unroll
      for (int i = 0; i < 2; ++i) {
        int r = posbase + i * 16 + llo + kk;
        f[i] = *(const short8_t*)(xb + r * 128 + ((cg ^ (r & 7)) << 4));
      }
#pragma unroll
      for (int i = 0; i < 2; ++i)
#pragma unroll
        for (int j = 0; j < 4; ++j)
          acc[i][j] = __builtin_amdgcn_mfma_f32_16x16x32_bf16(a[j], f[i], acc[i][j], 0, 0, 0);
    }

    // epilogue: +bias, pack 4 consecutive co, 8B stores (8 per wave)
    const int outRow = (SEGROWS == 1) ? u : u * 2 + (wv >> 2);
    const size_t rowbase = (size_t)outRow * (QLEN * 64);
#pragma unroll
    for (int j = 0; j < 4; ++j) {
#pragma unroll
      for (int i = 0; i < 2; ++i) {
        const int q = posbase + i * 16 + llo;
        float v0 = acc[i][j][0] + bv[j].x;
        float v1 = acc[i][j][1] + bv[j].y;
        float v2 = acc[i][j][2] + bv[j].z;
        float v3 = acc[i][j][3] + bv[j].w;
        unsigned lo, hi;
        asm("v_cvt_pk_bf16_f32 %0, %1, %2" : "=v"(lo) : "v"(v0), "v"(v1));
        asm("v_cvt_pk_bf16_f32 %0, %1, %2" : "=v"(hi) : "v"(v2), "v"(v3));
        uint2 ov; ov.x = lo; ov.y = hi;
        *(uint2*)(Y + rowbase + (size_t)q * 64 + j * 16 + lhi * 4) = ov;
      }
    }
    if (tt < 7) {
      // counted barrier: the 8 newest VMEM ops are this wave's stores;
      // waiting to <=8 retires all its stage(t+1) loads (in-order retire).
      asm volatile("s_waitcnt vmcnt(8)\n\ts_barrier" ::: "memory");
    }
  }
}

// ===== scan along OUTER dim P of [b][P][Q][ci], 4 ci/thread, depth-16 =====
// TRANS=1: write result transposed to [b][Q][P][ci] (outT) instead of in-place.
template<int PLEN, int QLEN, int REV, int TRANS>
__global__ __launch_bounds__(128) void scan_o4(unsigned short* __restrict__ conv,
                                               const unsigned short* __restrict__ prev,
                                               unsigned short* __restrict__ outT) {
  int idx = blockIdx.x * 128 + threadIdx.x;     // B * QLEN * 16
  int cq = idx & 15;
  int q  = (idx >> 4) % QLEN;
  int b  = idx / (16 * QLEN);
  const ptrdiff_t dp = (REV ? -1 : 1) * (ptrdiff_t)(QLEN * 64);
  const int p0 = REV ? PLEN - 1 : 0;
  size_t off = ((size_t)(b * PLEN + p0) * QLEN + q) * 64 + cq * 4;
  size_t offT = 0; ptrdiff_t dpT = 0;
  if (TRANS) {
    offT = ((size_t)(b * QLEN + q) * PLEN + p0) * 64 + cq * 4;
    dpT = (REV ? -1 : 1) * (ptrdiff_t)64;
  }
  uint2 pv = *(const uint2*)(prev + off);
  if (TRANS) *(uint2*)(outT + offT) = pv; else *(uint2*)(conv + off) = pv;
  float y0 = bf2f((unsigned short)pv.x), y1 = bf2f((unsigned short)(pv.x >> 16));
  float y2 = bf2f((unsigned short)pv.y), y3 = bf2f((unsigned short)(pv.y >> 16));
  uint2 c[16];
#pragma unroll
  for (int j = 0; j < 16; ++j) c[j] = *(const uint2*)(conv + off + (ptrdiff_t)(j + 1) * dp);
  for (int base = 1; base < PLEN; base += 16) {
#pragma unroll
    for (int j = 0; j < 16; ++j) {
      int s = base + j;
      if (s < PLEN) {
        off += dp;
        if (TRANS) offT += dpT;
        y0 = fmaxf(bf2f((unsigned short)c[j].x) + y0, 0.f);
        y1 = fmaxf(bf2f((unsigned short)(c[j].x >> 16)) + y1, 0.f);
        y2 = fmaxf(bf2f((unsigned short)c[j].y) + y2, 0.f);
        y3 = fmaxf(bf2f((unsigned short)(c[j].y >> 16)) + y3, 0.f);
        uint2 ov;
        ov.x = (unsigned)f2bf(y0) | ((unsigned)f2bf(y1) << 16);
        ov.y = (unsigned)f2bf(y2) | ((unsigned)f2bf(y3) << 16);
        if (TRANS) *(uint2*)(outT + offT) = ov; else *(uint2*)(conv + off) = ov;
        if (s + 16 < PLEN) c[j] = *(const uint2*)(conv + off + 16 * dp);
      }
    }
  }
}

// ===== scan_o2: in-place scan, 2 ci/thread (sweep 3) =====
template<int PLEN, int QLEN, int REV>
__global__ __launch_bounds__(128) void scan_o2(unsigned short* __restrict__ conv,
                                               const unsigned short* __restrict__ prev) {
  int idx = blockIdx.x * 128 + threadIdx.x;     // B * QLEN * 32
  int cp = idx & 31;
  int q  = (idx >> 5) % QLEN;
  int b  = idx / (32 * QLEN);
  const ptrdiff_t dp = (REV ? -1 : 1) * (ptrdiff_t)(QLEN * 64);
  const int p0 = REV ? PLEN - 1 : 0;
  size_t off = ((size_t)(b * PLEN + p0) * QLEN + q) * 64 + cp * 2;
  unsigned pv = *(const unsigned*)(prev + off);
  *(unsigned*)(conv + off) = pv;
  float y0 = bf2f((unsigned short)pv), y1 = bf2f((unsigned short)(pv >> 16));
  unsigned c[16];
#pragma unroll
  for (int j = 0; j < 16; ++j) c[j] = *(const unsigned*)(conv + off + (ptrdiff_t)(j + 1) * dp);
  for (int base = 1; base < PLEN; base += 16) {
#pragma unroll
    for (int j = 0; j < 16; ++j) {
      int s = base + j;
      if (s < PLEN) {
        off += dp;
        y0 = fmaxf(bf2f((unsigned short)c[j]) + y0, 0.f);
        y1 = fmaxf(bf2f((unsigned short)(c[j] >> 16)) + y1, 0.f);
        *(unsigned*)(conv + off) = (unsigned)f2bf(y0) | ((unsigned)f2bf(y1) << 16);
        if (s + 16 < PLEN) c[j] = *(const unsigned*)(conv + off + 16 * dp);
      }
    }
  }
}

// ===== scan4t: fused sweep-4 scan (rev along w on [b][w][h][ci]) + fp32 NCHW
// output via 32KB LDS tile; flush = full 256B-contiguous NCHW rows.
__global__ __launch_bounds__(128) void scan4t(const unsigned short* __restrict__ conv,
                                              const unsigned short* __restrict__ prev,
                                              float* __restrict__ out) {
  __shared__ unsigned tile[64 * 128];   // slot = wl*128 + hh*32 + (cp^(wl&31))
  const int t = threadIdx.x;
  const int cp = t & 31, hh = t >> 5;
  const int hg = blockIdx.x, b = blockIdx.y;
  const int h = hg * 4 + hh;
  const int wvid = t >> 6, wl = t & 63;

  const ptrdiff_t dp = -(ptrdiff_t)(H_ * 64);
  size_t off = ((size_t)(b * W_ + (W_ - 1)) * H_ + h) * 64 + cp * 2;

  auto flushChunk = [&](int w0) {
    __syncthreads();
    for (int p = 0; p < 64; ++p) {
      int combo = p * 2 + wvid;
      int fh = combo >> 5, fcp = combo & 31;
      unsigned v = tile[wl * 128 + fh * 32 + (fcp ^ (wl & 31))];
      size_t ob = ((size_t)(b * C_ + fcp * 2) * H_ + hg * 4 + fh) * W_ + w0 + wl;
      out[ob] = bf2f((unsigned short)v);
      out[ob + (size_t)H_ * W_] = bf2f((unsigned short)(v >> 16));
    }
    __syncthreads();
  };

  // s = 0 (w = 255): passthrough from prev, bit-exact
  unsigned pv = *(const unsigned*)(prev + off);
  float y0 = bf2f((unsigned short)pv), y1 = bf2f((unsigned short)(pv >> 16));
  tile[63 * 128 + hh * 32 + (cp ^ 31)] = pv;

  unsigned c[16];
#pragma unroll
  for (int j = 0; j < 16; ++j)
    c[j] = *(const unsigned*)(conv + off + (ptrdiff_t)(j + 1) * dp);

  for (int base = 1; base < W_; base += 16) {
#pragma unroll
    for (int j = 0; j < 16; ++j) {
      int s = base + j;
      off += dp;
      unsigned cv = c[j];
      y0 = fmaxf(bf2f((unsigned short)cv) + y0, 0.f);
      y1 = fmaxf(bf2f((unsigned short)(cv >> 16)) + y1, 0.f);
      int w = W_ - 1 - s;
      tile[(w & 63) * 128 + hh * 32 + (cp ^ (w & 31))] =
          (unsigned)f2bf(y0) | ((unsigned)f2bf(y1) << 16);
      if (s + 16 < W_) c[j] = *(const unsigned*)(conv + off + 16 * dp);
      if ((s & 63) == 63) flushChunk(w);   // w = 192,128,64,0
    }
  }
}

extern "C" void kernel_launch(void* const* d_in, const int* in_sizes, int n_in,
                              void* d_out, int out_size, void* d_ws, size_t ws_size,
                              hipStream_t stream) {
  const float* x    = (const float*)d_in[0];
  const float* w_ud = (const float*)d_in[1];
  const float* b_ud = (const float*)d_in[2];
  const float* w_du = (const float*)d_in[3];
  const float* b_du = (const float*)d_in[4];
  const float* w_lr = (const float*)d_in[5];
  const float* b_lr = (const float*)d_in[6];
  const float* w_rl = (const float*)d_in[7];
  const float* b_rl = (const float*)d_in[8];

  // ws: A[0,64M) Bb[64M,128M) Cc[128M,192M) A2 @192M, zeropage @192M+1M
  unsigned short* A  = (unsigned short*)d_ws;
  unsigned short* Bb = (unsigned short*)((char*)d_ws + 67108864);
  unsigned short* Cc = (unsigned short*)((char*)d_ws + 134217728);
  unsigned short* A2 = (unsigned short*)((char*)d_ws + 201326592);
  unsigned short* ZP = (unsigned short*)((char*)d_ws + 202375168);
  unsigned short* A2_ud = A2 + 0 * (C_ * KDIM_);
  unsigned short* A2_du = A2 + 1 * (C_ * KDIM_);
  unsigned short* A2_lr = A2 + 2 * (C_ * KDIM_);
  unsigned short* A2_rl = A2 + 3 * (C_ * KDIM_);

  dim3 pg((C_ * KDIM_ + 255) / 256, 4);
  prep_w_all<<<pg, 256, 0, stream>>>(w_ud, w_du, w_lr, w_rl, A2, (float*)ZP);

  transpose_in<<<dim3(4, H_, B_), 256, 0, stream>>>(x, A);

  // sweep 1 (ud): conv along W on [b][h][w][ci]; scan fwd along h
  conv8<W_><<<256, 512, 0, stream>>>(A, Bb, A2_ud, b_ud, ZP);
  scan_o4<H_, W_, 0, 0><<<512, 128, 0, stream>>>(Bb, A, nullptr);

  // sweep 2 (du): conv along W; scan rev along h, WRITE TRANSPOSED -> [b][w][h][ci]
  conv8<W_><<<256, 512, 0, stream>>>(Bb, Cc, A2_du, b_du, ZP);
  scan_o4<H_, W_, 1, 1><<<512, 128, 0, stream>>>(Cc, Bb, A);

  // sweep 3 (lr): conv along H (inner dim of flipped layout); scan fwd along w
  conv8<H_><<<256, 512, 0, stream>>>(A, Bb, A2_lr, b_lr, ZP);
  scan_o2<W_, H_, 0><<<512, 128, 0, stream>>>(Bb, A);

  // sweep 4 (rl): conv along H; scan rev along w, fused with NCHW fp32 output
  conv8<H_><<<256, 512, 0, stream>>>(Bb, Cc, A2_rl, b_rl, ZP);
  scan4t<<<dim3(32, B_), 128, 0, stream>>>(Cc, Bb, (float*)d_out);
}